// Round 1
// baseline (1295.370 us; speedup 1.0000x reference)
//
#include <hip/hip_runtime.h>
#include <math.h>

#define NEG_SLOPE 0.2f
#define SCAN_BS 1024

static __device__ __forceinline__ float leaky(float x) { return x > 0.f ? x : NEG_SLOPE * x; }

// ---------------- CSR build ----------------
__global__ void k_zero(int* p, int n) {
    int i = blockIdx.x * blockDim.x + threadIdx.x;
    if (i < n) p[i] = 0;
}

__global__ void k_hist(const int* __restrict__ dst, int* __restrict__ deg, int n_edges) {
    int e = blockIdx.x * blockDim.x + threadIdx.x;
    if (e < n_edges) atomicAdd(&deg[dst[e]], 1);
}

__global__ void k_scan1(const int* __restrict__ deg, int* __restrict__ row_ptr,
                        int* __restrict__ bsum, int n) {
    __shared__ int s[SCAN_BS];
    int t = threadIdx.x;
    int idx = blockIdx.x * SCAN_BS + t;
    int v = (idx < n) ? deg[idx] : 0;
    s[t] = v;
    __syncthreads();
    for (int off = 1; off < SCAN_BS; off <<= 1) {
        int x = (t >= off) ? s[t - off] : 0;
        __syncthreads();
        s[t] += x;
        __syncthreads();
    }
    if (idx < n) row_ptr[idx + 1] = s[t];
    if (t == SCAN_BS - 1) bsum[blockIdx.x] = s[t];
    if (idx == 0) row_ptr[0] = 0;
}

__global__ void k_scan2(const int* __restrict__ bsum, int* __restrict__ boff, int nb) {
    __shared__ int s[SCAN_BS];
    int t = threadIdx.x;
    int v = (t < nb) ? bsum[t] : 0;
    s[t] = v;
    __syncthreads();
    for (int off = 1; off < SCAN_BS; off <<= 1) {
        int x = (t >= off) ? s[t - off] : 0;
        __syncthreads();
        s[t] += x;
        __syncthreads();
    }
    if (t < nb) boff[t] = s[t] - v;  // exclusive
}

__global__ void k_scan3(int* __restrict__ row_ptr, const int* __restrict__ boff,
                        int* __restrict__ cursor, int n) {
    int idx = blockIdx.x * blockDim.x + threadIdx.x;
    if (idx < n) {
        int fin = row_ptr[idx + 1] + boff[idx >> 10];
        row_ptr[idx + 1] = fin;
        if (idx + 1 < n) cursor[idx + 1] = fin;
        if (idx == 0) cursor[0] = 0;
    }
}

__global__ void k_scatter(const int* __restrict__ src, const int* __restrict__ dst,
                          const float* __restrict__ ew, int* __restrict__ cursor,
                          int2* __restrict__ csr, int n_edges) {
    int e = blockIdx.x * blockDim.x + threadIdx.x;
    if (e < n_edges) {
        int d = dst[e];
        int p = atomicAdd(&cursor[d], 1);
        csr[p] = make_int2(src[e], __float_as_int(ew[e]));
    }
}

// ---------------- GEMM: C[n][128] = A[n][128] * B[128][128] ----------------
// tile 64 rows x 64 cols, block 256 threads, each thread 4x4 outputs.
__global__ __launch_bounds__(256) void k_gemm(const float* __restrict__ A,
                                              const float* __restrict__ B,
                                              float* __restrict__ C, int n) {
    __shared__ float As[64 * 128];  // As[r][k]
    __shared__ float Bs[128 * 64];  // Bs[k][c]
    int t = threadIdx.x;
    int row0 = blockIdx.x * 64;
    int colbase = blockIdx.y * 64;

    // stage A tile (coalesced float4 row-major)
    {
        int ac = (t & 31) * 4;
        int rof = t >> 5;  // 0..7
        for (int it = 0; it < 8; ++it) {
            int rr = rof + it * 8;
            int r = row0 + rr;
            float4 v = make_float4(0.f, 0.f, 0.f, 0.f);
            if (r < n) v = *(const float4*)(A + (size_t)r * 128 + ac);
            *(float4*)(As + rr * 128 + ac) = v;
        }
    }
    // stage B strip
    {
        int c0 = (t & 15) * 4;
        int kr = t >> 4;  // 0..15
        for (int it = 0; it < 8; ++it) {
            int k = kr + it * 16;
            float4 v = *(const float4*)(B + (size_t)k * 128 + colbase + c0);
            *(float4*)(Bs + k * 64 + c0) = v;
        }
    }
    __syncthreads();

    int r0 = (t >> 4) * 4;
    int c0 = (t & 15) * 4;
    float acc[4][4];
#pragma unroll
    for (int i = 0; i < 4; i++)
#pragma unroll
        for (int j = 0; j < 4; j++) acc[i][j] = 0.f;

#pragma unroll 8
    for (int k = 0; k < 128; k++) {
        float4 b = *(const float4*)(Bs + k * 64 + c0);
        float a0 = As[(r0 + 0) * 128 + k];
        float a1 = As[(r0 + 1) * 128 + k];
        float a2 = As[(r0 + 2) * 128 + k];
        float a3 = As[(r0 + 3) * 128 + k];
        acc[0][0] = fmaf(a0, b.x, acc[0][0]); acc[0][1] = fmaf(a0, b.y, acc[0][1]);
        acc[0][2] = fmaf(a0, b.z, acc[0][2]); acc[0][3] = fmaf(a0, b.w, acc[0][3]);
        acc[1][0] = fmaf(a1, b.x, acc[1][0]); acc[1][1] = fmaf(a1, b.y, acc[1][1]);
        acc[1][2] = fmaf(a1, b.z, acc[1][2]); acc[1][3] = fmaf(a1, b.w, acc[1][3]);
        acc[2][0] = fmaf(a2, b.x, acc[2][0]); acc[2][1] = fmaf(a2, b.y, acc[2][1]);
        acc[2][2] = fmaf(a2, b.z, acc[2][2]); acc[2][3] = fmaf(a2, b.w, acc[2][3]);
        acc[3][0] = fmaf(a3, b.x, acc[3][0]); acc[3][1] = fmaf(a3, b.y, acc[3][1]);
        acc[3][2] = fmaf(a3, b.z, acc[3][2]); acc[3][3] = fmaf(a3, b.w, acc[3][3]);
    }

#pragma unroll
    for (int i = 0; i < 4; i++) {
        int r = row0 + r0 + i;
        if (r < n) {
            float4 v = make_float4(acc[i][0], acc[i][1], acc[i][2], acc[i][3]);
            *(float4*)(C + (size_t)r * 128 + colbase + c0) = v;
        }
    }
}

// ---------------- attention scores el/er ----------------
__global__ void k_scores(const float* __restrict__ feat, const float* __restrict__ al,
                         const float* __restrict__ ar, float* __restrict__ el,
                         float* __restrict__ er, int n) {
    int t = blockIdx.x * blockDim.x + threadIdx.x;
    if (t >= n * 4) return;
    int nd = t >> 2, h = t & 3;
    const float4* f4 = (const float4*)(feat + (size_t)nd * 128 + h * 32);
    const float4* a4 = (const float4*)(al + h * 32);
    const float4* b4 = (const float4*)(ar + h * 32);
    float sl = 0.f, sr = 0.f;
#pragma unroll
    for (int j = 0; j < 8; j++) {
        float4 f = f4[j];
        float4 a = a4[j];
        float4 b = b4[j];
        sl += f.x * a.x + f.y * a.y + f.z * a.z + f.w * a.w;
        sr += f.x * b.x + f.y * b.y + f.z * b.z + f.w * b.w;
    }
    el[t] = sl;
    er[t] = sr;
}

// ---------------- per-dst-node softmax + aggregate ----------------
// block = 128 threads (2 waves). lane owns features 2*lane, 2*lane+1 (same head).
__global__ __launch_bounds__(128) void k_edge(const int* __restrict__ row_ptr,
                                              const int2* __restrict__ csr,
                                              const float* __restrict__ feat,
                                              const float* __restrict__ el,
                                              const float* __restrict__ er,
                                              const float* __restrict__ bias,
                                              float* __restrict__ out) {
    int v = blockIdx.x;
    int t = threadIdx.x;
    int wv = t >> 6;
    int lane = t & 63;
    int h = lane >> 4;  // head of features 2*lane, 2*lane+1

    int start = row_ptr[v];
    int end = row_ptr[v + 1];

    float4 erv = *(const float4*)(er + (size_t)v * 4);

    // pass 1: per-head max over incoming edges (all 128 threads, edge-strided)
    float4 mx = make_float4(-1e30f, -1e30f, -1e30f, -1e30f);
    for (int i = start + t; i < end; i += 128) {
        int2 c = csr[i];
        float4 e4 = *(const float4*)(el + (size_t)c.x * 4);
        mx.x = fmaxf(mx.x, leaky(e4.x + erv.x));
        mx.y = fmaxf(mx.y, leaky(e4.y + erv.y));
        mx.z = fmaxf(mx.z, leaky(e4.z + erv.z));
        mx.w = fmaxf(mx.w, leaky(e4.w + erv.w));
    }
#pragma unroll
    for (int m = 1; m < 64; m <<= 1) {
        mx.x = fmaxf(mx.x, __shfl_xor(mx.x, m));
        mx.y = fmaxf(mx.y, __shfl_xor(mx.y, m));
        mx.z = fmaxf(mx.z, __shfl_xor(mx.z, m));
        mx.w = fmaxf(mx.w, __shfl_xor(mx.w, m));
    }
    __shared__ float4 smx[2];
    __shared__ float s1[4];
    __shared__ float sa[64], sb[64];
    if (lane == 0) smx[wv] = mx;
    __syncthreads();
    {
        float4 m0 = smx[0], m1 = smx[1];
        mx.x = fmaxf(m0.x, m1.x);
        mx.y = fmaxf(m0.y, m1.y);
        mx.z = fmaxf(m0.z, m1.z);
        mx.w = fmaxf(m0.w, m1.w);
    }
    float m_h = (h == 0) ? mx.x : (h == 1) ? mx.y : (h == 2) ? mx.z : mx.w;
    float er_h = (h == 0) ? erv.x : (h == 1) ? erv.y : (h == 2) ? erv.z : erv.w;

    // pass 2: exp/sum + weighted feature accumulation; waves split edges (even/odd)
    float acc0 = 0.f, acc1 = 0.f, ssum = 0.f;
    const float2* feat2 = (const float2*)feat;
    for (int i = start + wv; i < end; i += 2) {
        int2 c = csr[i];
        float elh = el[(size_t)c.x * 4 + h];
        float ee = elh + er_h;
        ee = ee > 0.f ? ee : NEG_SLOPE * ee;
        float p = __expf(ee - m_h);
        ssum += p;
        float2 fv = feat2[(size_t)c.x * 64 + lane];
        float pw = p * __int_as_float(c.y);
        acc0 = fmaf(pw, fv.x, acc0);
        acc1 = fmaf(pw, fv.y, acc1);
    }
    if (wv == 1) {
        sa[lane] = acc0;
        sb[lane] = acc1;
        if ((lane & 15) == 0) s1[h] = ssum;
    }
    __syncthreads();
    if (wv == 0) {
        acc0 += sa[lane];
        acc1 += sb[lane];
        ssum += s1[h];
        float inv = 1.f / fmaxf(ssum, 1e-20f);
        int f0 = lane * 2;
        float o0 = fmaf(acc0, inv, bias[f0]);
        float o1 = fmaf(acc1, inv, bias[f0 + 1]);
        o0 = o0 > 0.f ? o0 : __expf(o0) - 1.f;
        o1 = o1 > 0.f ? o1 : __expf(o1) - 1.f;
        *(float2*)(out + (size_t)v * 128 + f0) = make_float2(o0, o1);
    }
}

// ---------------- launch ----------------
extern "C" void kernel_launch(void* const* d_in, const int* in_sizes, int n_in,
                              void* d_out, int out_size, void* d_ws, size_t ws_size,
                              hipStream_t stream) {
    int n_nodes = in_sizes[0] / 128;
    int n_edges = in_sizes[1];

    const float* in_feat = (const float*)d_in[0];
    const float* ew = (const float*)d_in[1];
    const int* src = (const int*)d_in[2];
    const int* dst = (const int*)d_in[3];
    const float* W0 = (const float*)d_in[4];
    const float* al0 = (const float*)d_in[5];
    const float* ar0 = (const float*)d_in[6];
    const float* b0 = (const float*)d_in[7];
    const float* W1 = (const float*)d_in[8];
    const float* al1 = (const float*)d_in[9];
    const float* ar1 = (const float*)d_in[10];
    const float* b1 = (const float*)d_in[11];
    float* out = (float*)d_out;

    char* w = (char*)d_ws;
    auto alloc = [&](size_t bytes) {
        char* p = w;
        w += (bytes + 255) & ~(size_t)255;
        return p;
    };
    float* feat = (float*)alloc((size_t)n_nodes * 128 * 4);
    float* h1 = (float*)alloc((size_t)n_nodes * 128 * 4);
    float* el = (float*)alloc((size_t)n_nodes * 4 * 4);
    float* er = (float*)alloc((size_t)n_nodes * 4 * 4);
    int* deg = (int*)alloc((size_t)n_nodes * 4);
    int* row_ptr = (int*)alloc(((size_t)n_nodes + 1) * 4);
    int* cursor = (int*)alloc((size_t)n_nodes * 4);
    int* bsum = (int*)alloc(SCAN_BS * 4);
    int* boff = (int*)alloc(SCAN_BS * 4);
    int2* csr = (int2*)alloc((size_t)n_edges * 8);

    int tb = 256;
    int gb_n = (n_nodes + tb - 1) / tb;
    int gb_e = (n_edges + tb - 1) / tb;
    int nb = (n_nodes + SCAN_BS - 1) / SCAN_BS;

    // CSR build (dst-sorted adjacency), rebuilt every call
    k_zero<<<gb_n, tb, 0, stream>>>(deg, n_nodes);
    k_hist<<<gb_e, tb, 0, stream>>>(dst, deg, n_edges);
    k_scan1<<<nb, SCAN_BS, 0, stream>>>(deg, row_ptr, bsum, n_nodes);
    k_scan2<<<1, SCAN_BS, 0, stream>>>(bsum, boff, nb);
    k_scan3<<<gb_n, tb, 0, stream>>>(row_ptr, boff, cursor, n_nodes);
    k_scatter<<<gb_e, tb, 0, stream>>>(src, dst, ew, cursor, csr, n_edges);

    dim3 gg((n_nodes + 63) / 64, 2);
    int gs = (n_nodes * 4 + tb - 1) / tb;

    // layer 1
    k_gemm<<<gg, 256, 0, stream>>>(in_feat, W0, feat, n_nodes);
    k_scores<<<gs, tb, 0, stream>>>(feat, al0, ar0, el, er, n_nodes);
    k_edge<<<n_nodes, 128, 0, stream>>>(row_ptr, csr, feat, el, er, b0, h1);

    // layer 2
    k_gemm<<<gg, 256, 0, stream>>>(h1, W1, feat, n_nodes);
    k_scores<<<gs, tb, 0, stream>>>(feat, al1, ar1, el, er, n_nodes);
    k_edge<<<n_nodes, 128, 0, stream>>>(row_ptr, csr, feat, el, er, b1, out);
}

// Round 2
// 1141.655 us; speedup vs baseline: 1.1346x; 1.1346x over previous
//
#include <hip/hip_runtime.h>
#include <math.h>

#define NEG_SLOPE 0.2f
#define SCAN_BS 1024

static __device__ __forceinline__ float leaky(float x) { return x > 0.f ? x : NEG_SLOPE * x; }

// ---------------- CSR build ----------------
__global__ void k_zero(int* p, int n) {
    int i = blockIdx.x * blockDim.x + threadIdx.x;
    if (i < n) p[i] = 0;
}

__global__ void k_hist(const int* __restrict__ dst, int* __restrict__ deg, int n_edges) {
    int e = blockIdx.x * blockDim.x + threadIdx.x;
    if (e < n_edges) atomicAdd(&deg[dst[e]], 1);
}

__global__ void k_scan1(const int* __restrict__ deg, int* __restrict__ row_ptr,
                        int* __restrict__ bsum, int n) {
    __shared__ int s[SCAN_BS];
    int t = threadIdx.x;
    int idx = blockIdx.x * SCAN_BS + t;
    int v = (idx < n) ? deg[idx] : 0;
    s[t] = v;
    __syncthreads();
    for (int off = 1; off < SCAN_BS; off <<= 1) {
        int x = (t >= off) ? s[t - off] : 0;
        __syncthreads();
        s[t] += x;
        __syncthreads();
    }
    if (idx < n) row_ptr[idx + 1] = s[t];
    if (t == SCAN_BS - 1) bsum[blockIdx.x] = s[t];
    if (idx == 0) row_ptr[0] = 0;
}

__global__ void k_scan2(const int* __restrict__ bsum, int* __restrict__ boff, int nb) {
    __shared__ int s[SCAN_BS];
    int t = threadIdx.x;
    int v = (t < nb) ? bsum[t] : 0;
    s[t] = v;
    __syncthreads();
    for (int off = 1; off < SCAN_BS; off <<= 1) {
        int x = (t >= off) ? s[t - off] : 0;
        __syncthreads();
        s[t] += x;
        __syncthreads();
    }
    if (t < nb) boff[t] = s[t] - v;  // exclusive
}

__global__ void k_scan3(int* __restrict__ row_ptr, const int* __restrict__ boff,
                        int* __restrict__ cursor, int n) {
    int idx = blockIdx.x * blockDim.x + threadIdx.x;
    if (idx < n) {
        int fin = row_ptr[idx + 1] + boff[idx >> 10];
        row_ptr[idx + 1] = fin;
        if (idx + 1 < n) cursor[idx + 1] = fin;
        if (idx == 0) cursor[0] = 0;
    }
}

__global__ void k_scatter(const int* __restrict__ src, const int* __restrict__ dst,
                          const float* __restrict__ ew, int* __restrict__ cursor,
                          int2* __restrict__ csr, int n_edges) {
    int e = blockIdx.x * blockDim.x + threadIdx.x;
    if (e < n_edges) {
        int d = dst[e];
        int p = atomicAdd(&cursor[d], 1);
        csr[p] = make_int2(src[e], __float_as_int(ew[e]));
    }
}

// ---------------- GEMM + fused attention scores ----------------
// C[n][128] = A[n][128] * B[128][128]; also el/er for the 2 heads this
// block's 64-col strip covers. tile 64x64, block 256, 4x4 per thread.
__global__ __launch_bounds__(256) void k_gemm(const float* __restrict__ A,
                                              const float* __restrict__ B,
                                              float* __restrict__ C,
                                              const float* __restrict__ al,
                                              const float* __restrict__ ar,
                                              float* __restrict__ el,
                                              float* __restrict__ er, int n) {
    __shared__ float As[64 * 128];  // As[r][k]
    __shared__ float Bs[128 * 64];  // Bs[k][c]
    int t = threadIdx.x;
    int row0 = blockIdx.x * 64;
    int colbase = blockIdx.y * 64;

    // stage A tile (coalesced float4 row-major)
    {
        int ac = (t & 31) * 4;
        int rof = t >> 5;  // 0..7
        for (int it = 0; it < 8; ++it) {
            int rr = rof + it * 8;
            int r = row0 + rr;
            float4 v = make_float4(0.f, 0.f, 0.f, 0.f);
            if (r < n) v = *(const float4*)(A + (size_t)r * 128 + ac);
            *(float4*)(As + rr * 128 + ac) = v;
        }
    }
    // stage B strip
    {
        int c0 = (t & 15) * 4;
        int kr = t >> 4;  // 0..15
        for (int it = 0; it < 8; ++it) {
            int k = kr + it * 16;
            float4 v = *(const float4*)(B + (size_t)k * 128 + colbase + c0);
            *(float4*)(Bs + k * 64 + c0) = v;
        }
    }
    __syncthreads();

    int r0 = (t >> 4) * 4;
    int c0 = (t & 15) * 4;
    float acc[4][4];
#pragma unroll
    for (int i = 0; i < 4; i++)
#pragma unroll
        for (int j = 0; j < 4; j++) acc[i][j] = 0.f;

#pragma unroll 8
    for (int k = 0; k < 128; k++) {
        float4 b = *(const float4*)(Bs + k * 64 + c0);
        float a0 = As[(r0 + 0) * 128 + k];
        float a1 = As[(r0 + 1) * 128 + k];
        float a2 = As[(r0 + 2) * 128 + k];
        float a3 = As[(r0 + 3) * 128 + k];
        acc[0][0] = fmaf(a0, b.x, acc[0][0]); acc[0][1] = fmaf(a0, b.y, acc[0][1]);
        acc[0][2] = fmaf(a0, b.z, acc[0][2]); acc[0][3] = fmaf(a0, b.w, acc[0][3]);
        acc[1][0] = fmaf(a1, b.x, acc[1][0]); acc[1][1] = fmaf(a1, b.y, acc[1][1]);
        acc[1][2] = fmaf(a1, b.z, acc[1][2]); acc[1][3] = fmaf(a1, b.w, acc[1][3]);
        acc[2][0] = fmaf(a2, b.x, acc[2][0]); acc[2][1] = fmaf(a2, b.y, acc[2][1]);
        acc[2][2] = fmaf(a2, b.z, acc[2][2]); acc[2][3] = fmaf(a2, b.w, acc[2][3]);
        acc[3][0] = fmaf(a3, b.x, acc[3][0]); acc[3][1] = fmaf(a3, b.y, acc[3][1]);
        acc[3][2] = fmaf(a3, b.z, acc[3][2]); acc[3][3] = fmaf(a3, b.w, acc[3][3]);
    }

#pragma unroll
    for (int i = 0; i < 4; i++) {
        int r = row0 + r0 + i;
        if (r < n) {
            float4 v = make_float4(acc[i][0], acc[i][1], acc[i][2], acc[i][3]);
            *(float4*)(C + (size_t)r * 128 + colbase + c0) = v;
        }
    }

    // fused el/er: this block's 64-col strip covers heads 2*by, 2*by+1.
    // thread covers cols c0..c0+3 -> head hg; reduce over the 8 threads
    // sharing (row group, head) via shfl (they are consecutive lanes).
    {
        int hg = blockIdx.y * 2 + ((t >> 3) & 1);       // global head of c0
        float4 a4 = *(const float4*)(al + hg * 32 + (t & 7) * 4);
        float4 b4 = *(const float4*)(ar + hg * 32 + (t & 7) * 4);
        float pel[4], per[4];
#pragma unroll
        for (int i = 0; i < 4; i++) {
            pel[i] = acc[i][0] * a4.x + acc[i][1] * a4.y + acc[i][2] * a4.z + acc[i][3] * a4.w;
            per[i] = acc[i][0] * b4.x + acc[i][1] * b4.y + acc[i][2] * b4.z + acc[i][3] * b4.w;
        }
#pragma unroll
        for (int m = 1; m < 8; m <<= 1) {
#pragma unroll
            for (int i = 0; i < 4; i++) {
                pel[i] += __shfl_xor(pel[i], m);
                per[i] += __shfl_xor(per[i], m);
            }
        }
        if ((t & 7) == 0) {
#pragma unroll
            for (int i = 0; i < 4; i++) {
                int r = row0 + r0 + i;
                if (r < n) {
                    el[(size_t)r * 4 + hg] = pel[i];
                    er[(size_t)r * 4 + hg] = per[i];
                }
            }
        }
    }
}

// ---------------- per-dst-node softmax + aggregate (single pass, no max) ----------------
// softmax(e) == exp(e)/sum(exp(e)); |e| is small here so no max-shift needed.
// block = 128 threads (2 waves). lane owns features 2*lane, 2*lane+1 (same head).
// wave wv processes edge pairs {start+2wv, start+2wv+1}, stride 4 -> 4-deep MLP.
__global__ __launch_bounds__(128) void k_edge(const int* __restrict__ row_ptr,
                                              const int2* __restrict__ csr,
                                              const float* __restrict__ feat,
                                              const float* __restrict__ el,
                                              const float* __restrict__ er,
                                              const float* __restrict__ bias,
                                              float* __restrict__ out) {
    int v = blockIdx.x;
    int t = threadIdx.x;
    int wv = t >> 6;
    int lane = t & 63;
    int h = lane >> 4;  // head of features 2*lane, 2*lane+1

    int start = row_ptr[v];
    int end = row_ptr[v + 1];

    float er_h = er[(size_t)v * 4 + h];

    float acc0 = 0.f, acc1 = 0.f, ssum = 0.f;
    const float2* feat2 = (const float2*)feat;

    for (int i = start + wv * 2; i < end; i += 4) {
        bool hb = (i + 1) < end;
        int2 ca = csr[i];
        int2 cb = hb ? csr[i + 1] : ca;
        // issue all independent loads first (MLP)
        float ela = el[(size_t)ca.x * 4 + h];
        float elb = el[(size_t)cb.x * 4 + h];
        float2 fa = feat2[(size_t)ca.x * 64 + lane];
        float2 fb = feat2[(size_t)cb.x * 64 + lane];
        float ea = leaky(ela + er_h);
        float eb = leaky(elb + er_h);
        float pa = __expf(ea);
        float pb = hb ? __expf(eb) : 0.f;
        ssum += pa + pb;
        float pwa = pa * __int_as_float(ca.y);
        float pwb = pb * __int_as_float(cb.y);
        acc0 = fmaf(pwa, fa.x, acc0);
        acc1 = fmaf(pwa, fa.y, acc1);
        acc0 = fmaf(pwb, fb.x, acc0);
        acc1 = fmaf(pwb, fb.y, acc1);
    }

    __shared__ float sa[64], sb[64], s1[4];
    if (wv == 1) {
        sa[lane] = acc0;
        sb[lane] = acc1;
        if ((lane & 15) == 0) s1[h] = ssum;
    }
    __syncthreads();
    if (wv == 0) {
        acc0 += sa[lane];
        acc1 += sb[lane];
        ssum += s1[h];
        float inv = 1.f / fmaxf(ssum, 1e-20f);
        int f0 = lane * 2;
        float o0 = fmaf(acc0, inv, bias[f0]);
        float o1 = fmaf(acc1, inv, bias[f0 + 1]);
        o0 = o0 > 0.f ? o0 : __expf(o0) - 1.f;
        o1 = o1 > 0.f ? o1 : __expf(o1) - 1.f;
        *(float2*)(out + (size_t)v * 128 + f0) = make_float2(o0, o1);
    }
}

// ---------------- launch ----------------
extern "C" void kernel_launch(void* const* d_in, const int* in_sizes, int n_in,
                              void* d_out, int out_size, void* d_ws, size_t ws_size,
                              hipStream_t stream) {
    int n_nodes = in_sizes[0] / 128;
    int n_edges = in_sizes[1];

    const float* in_feat = (const float*)d_in[0];
    const float* ew = (const float*)d_in[1];
    const int* src = (const int*)d_in[2];
    const int* dst = (const int*)d_in[3];
    const float* W0 = (const float*)d_in[4];
    const float* al0 = (const float*)d_in[5];
    const float* ar0 = (const float*)d_in[6];
    const float* b0 = (const float*)d_in[7];
    const float* W1 = (const float*)d_in[8];
    const float* al1 = (const float*)d_in[9];
    const float* ar1 = (const float*)d_in[10];
    const float* b1 = (const float*)d_in[11];
    float* out = (float*)d_out;

    char* w = (char*)d_ws;
    auto alloc = [&](size_t bytes) {
        char* p = w;
        w += (bytes + 255) & ~(size_t)255;
        return p;
    };
    float* feat = (float*)alloc((size_t)n_nodes * 128 * 4);
    float* h1 = (float*)alloc((size_t)n_nodes * 128 * 4);
    float* el = (float*)alloc((size_t)n_nodes * 4 * 4);
    float* er = (float*)alloc((size_t)n_nodes * 4 * 4);
    int* deg = (int*)alloc((size_t)n_nodes * 4);
    int* row_ptr = (int*)alloc(((size_t)n_nodes + 1) * 4);
    int* cursor = (int*)alloc((size_t)n_nodes * 4);
    int* bsum = (int*)alloc(SCAN_BS * 4);
    int* boff = (int*)alloc(SCAN_BS * 4);
    int2* csr = (int2*)alloc((size_t)n_edges * 8);

    int tb = 256;
    int gb_n = (n_nodes + tb - 1) / tb;
    int gb_e = (n_edges + tb - 1) / tb;
    int nb = (n_nodes + SCAN_BS - 1) / SCAN_BS;

    // CSR build (dst-sorted adjacency), rebuilt every call
    k_zero<<<gb_n, tb, 0, stream>>>(deg, n_nodes);
    k_hist<<<gb_e, tb, 0, stream>>>(dst, deg, n_edges);
    k_scan1<<<nb, SCAN_BS, 0, stream>>>(deg, row_ptr, bsum, n_nodes);
    k_scan2<<<1, SCAN_BS, 0, stream>>>(bsum, boff, nb);
    k_scan3<<<gb_n, tb, 0, stream>>>(row_ptr, boff, cursor, n_nodes);
    k_scatter<<<gb_e, tb, 0, stream>>>(src, dst, ew, cursor, csr, n_edges);

    dim3 gg((n_nodes + 63) / 64, 2);

    // layer 1
    k_gemm<<<gg, 256, 0, stream>>>(in_feat, W0, feat, al0, ar0, el, er, n_nodes);
    k_edge<<<n_nodes, 128, 0, stream>>>(row_ptr, csr, feat, el, er, b0, h1);

    // layer 2
    k_gemm<<<gg, 256, 0, stream>>>(h1, W1, feat, al1, ar1, el, er, n_nodes);
    k_edge<<<n_nodes, 128, 0, stream>>>(row_ptr, csr, feat, el, er, b1, out);
}

// Round 7
// 1078.784 us; speedup vs baseline: 1.2008x; 1.0583x over previous
//
#include <hip/hip_runtime.h>
#include <math.h>

#define NEG_SLOPE 0.2f
#define SCAN_BS 1024

static __device__ __forceinline__ float leaky(float x) { return x > 0.f ? x : NEG_SLOPE * x; }

// ---------------- CSR build ----------------
__global__ void k_zero(int* p, int n) {
    int i = blockIdx.x * blockDim.x + threadIdx.x;
    if (i < n) p[i] = 0;
}

__global__ void k_hist(const int* __restrict__ dst, int* __restrict__ deg, int n_edges) {
    int e = blockIdx.x * blockDim.x + threadIdx.x;
    if (e < n_edges) atomicAdd(&deg[dst[e]], 1);
}

__global__ void k_scan1(const int* __restrict__ deg, int* __restrict__ row_ptr,
                        int* __restrict__ bsum, int n) {
    __shared__ int s[SCAN_BS];
    int t = threadIdx.x;
    int idx = blockIdx.x * SCAN_BS + t;
    int v = (idx < n) ? deg[idx] : 0;
    s[t] = v;
    __syncthreads();
    for (int off = 1; off < SCAN_BS; off <<= 1) {
        int x = (t >= off) ? s[t - off] : 0;
        __syncthreads();
        s[t] += x;
        __syncthreads();
    }
    if (idx < n) row_ptr[idx + 1] = s[t];
    if (t == SCAN_BS - 1) bsum[blockIdx.x] = s[t];
    if (idx == 0) row_ptr[0] = 0;
}

__global__ void k_scan2(const int* __restrict__ bsum, int* __restrict__ boff, int nb) {
    __shared__ int s[SCAN_BS];
    int t = threadIdx.x;
    int v = (t < nb) ? bsum[t] : 0;
    s[t] = v;
    __syncthreads();
    for (int off = 1; off < SCAN_BS; off <<= 1) {
        int x = (t >= off) ? s[t - off] : 0;
        __syncthreads();
        s[t] += x;
        __syncthreads();
    }
    if (t < nb) boff[t] = s[t] - v;  // exclusive
}

__global__ void k_scan3(int* __restrict__ row_ptr, const int* __restrict__ boff,
                        int* __restrict__ cursor, int n) {
    int idx = blockIdx.x * blockDim.x + threadIdx.x;
    if (idx < n) {
        int fin = row_ptr[idx + 1] + boff[idx >> 10];
        row_ptr[idx + 1] = fin;
        if (idx + 1 < n) cursor[idx + 1] = fin;
        if (idx == 0) cursor[0] = 0;
    }
}

__global__ void k_scatter(const int* __restrict__ src, const int* __restrict__ dst,
                          const float* __restrict__ ew, int* __restrict__ cursor,
                          int2* __restrict__ csr, int n_edges) {
    int e = blockIdx.x * blockDim.x + threadIdx.x;
    if (e < n_edges) {
        int d = dst[e];
        int p = atomicAdd(&cursor[d], 1);
        csr[p] = make_int2(src[e], __float_as_int(ew[e]));
    }
}

// ---------------- GEMM + fused attention scores (round-2 measured-good) ----
// C[n][128] = A[n][128] * B[128][128]; el/er for the 2 heads of this 64-col
// strip. tile 64x64, block 256, 4x4 per thread.
__global__ __launch_bounds__(256) void k_gemm(const float* __restrict__ A,
                                              const float* __restrict__ B,
                                              float* __restrict__ C,
                                              const float* __restrict__ al,
                                              const float* __restrict__ ar,
                                              float* __restrict__ el,
                                              float* __restrict__ er, int n) {
    __shared__ float As[64 * 128];  // As[r][k]
    __shared__ float Bs[128 * 64];  // Bs[k][c]
    int t = threadIdx.x;
    int row0 = blockIdx.x * 64;
    int colbase = blockIdx.y * 64;

    // stage A tile (coalesced float4 row-major)
    {
        int ac = (t & 31) * 4;
        int rof = t >> 5;  // 0..7
        for (int it = 0; it < 8; ++it) {
            int rr = rof + it * 8;
            int r = row0 + rr;
            float4 v = make_float4(0.f, 0.f, 0.f, 0.f);
            if (r < n) v = *(const float4*)(A + (size_t)r * 128 + ac);
            *(float4*)(As + rr * 128 + ac) = v;
        }
    }
    // stage B strip
    {
        int c0 = (t & 15) * 4;
        int kr = t >> 4;  // 0..15
        for (int it = 0; it < 8; ++it) {
            int k = kr + it * 16;
            float4 v = *(const float4*)(B + (size_t)k * 128 + colbase + c0);
            *(float4*)(Bs + k * 64 + c0) = v;
        }
    }
    __syncthreads();

    int r0 = (t >> 4) * 4;
    int c0 = (t & 15) * 4;
    float acc[4][4];
#pragma unroll
    for (int i = 0; i < 4; i++)
#pragma unroll
        for (int j = 0; j < 4; j++) acc[i][j] = 0.f;

#pragma unroll 8
    for (int k = 0; k < 128; k++) {
        float4 b = *(const float4*)(Bs + k * 64 + c0);
        float a0 = As[(r0 + 0) * 128 + k];
        float a1 = As[(r0 + 1) * 128 + k];
        float a2 = As[(r0 + 2) * 128 + k];
        float a3 = As[(r0 + 3) * 128 + k];
        acc[0][0] = fmaf(a0, b.x, acc[0][0]); acc[0][1] = fmaf(a0, b.y, acc[0][1]);
        acc[0][2] = fmaf(a0, b.z, acc[0][2]); acc[0][3] = fmaf(a0, b.w, acc[0][3]);
        acc[1][0] = fmaf(a1, b.x, acc[1][0]); acc[1][1] = fmaf(a1, b.y, acc[1][1]);
        acc[1][2] = fmaf(a1, b.z, acc[1][2]); acc[1][3] = fmaf(a1, b.w, acc[1][3]);
        acc[2][0] = fmaf(a2, b.x, acc[2][0]); acc[2][1] = fmaf(a2, b.y, acc[2][1]);
        acc[2][2] = fmaf(a2, b.z, acc[2][2]); acc[2][3] = fmaf(a2, b.w, acc[2][3]);
        acc[3][0] = fmaf(a3, b.x, acc[3][0]); acc[3][1] = fmaf(a3, b.y, acc[3][1]);
        acc[3][2] = fmaf(a3, b.z, acc[3][2]); acc[3][3] = fmaf(a3, b.w, acc[3][3]);
    }

#pragma unroll
    for (int i = 0; i < 4; i++) {
        int r = row0 + r0 + i;
        if (r < n) {
            float4 v = make_float4(acc[i][0], acc[i][1], acc[i][2], acc[i][3]);
            *(float4*)(C + (size_t)r * 128 + colbase + c0) = v;
        }
    }

    // fused el/er: strip covers heads 2*by, 2*by+1; 8 consecutive lanes share
    // (row group, head) -> shfl reduce.
    {
        int hg = blockIdx.y * 2 + ((t >> 3) & 1);
        float4 a4 = *(const float4*)(al + hg * 32 + (t & 7) * 4);
        float4 b4 = *(const float4*)(ar + hg * 32 + (t & 7) * 4);
        float pel[4], per[4];
#pragma unroll
        for (int i = 0; i < 4; i++) {
            pel[i] = acc[i][0] * a4.x + acc[i][1] * a4.y + acc[i][2] * a4.z + acc[i][3] * a4.w;
            per[i] = acc[i][0] * b4.x + acc[i][1] * b4.y + acc[i][2] * b4.z + acc[i][3] * b4.w;
        }
#pragma unroll
        for (int m = 1; m < 8; m <<= 1) {
#pragma unroll
            for (int i = 0; i < 4; i++) {
                pel[i] += __shfl_xor(pel[i], m);
                per[i] += __shfl_xor(per[i], m);
            }
        }
        if ((t & 7) == 0) {
#pragma unroll
            for (int i = 0; i < 4; i++) {
                int r = row0 + r0 + i;
                if (r < n) {
                    el[(size_t)r * 4 + hg] = pel[i];
                    er[(size_t)r * 4 + hg] = per[i];
                }
            }
        }
    }
}

// ---------------- per-dst-node softmax + aggregate ----------------
// one WAVE per node; lane owns features 2*lane, 2*lane+1 (head lane>>4).
// No CSR padding: 4-way unroll with clamped indices (always in-bounds when
// the loop runs) and zero-masked p for the tail. ssum needs no reduction:
// every lane of the wave sees every edge of its node. No LDS, no barriers.
__global__ __launch_bounds__(256) void k_edge(const int* __restrict__ row_ptr,
                                              const int2* __restrict__ csr,
                                              const float* __restrict__ feat,
                                              const float* __restrict__ el,
                                              const float* __restrict__ er,
                                              const float* __restrict__ bias,
                                              float* __restrict__ out, int n) {
    int wv = threadIdx.x >> 6;
    int v = blockIdx.x * 4 + wv;
    if (v >= n) return;
    int lane = threadIdx.x & 63;
    int h = lane >> 4;

    int start = row_ptr[v];
    int end = row_ptr[v + 1];
    float er_h = er[(size_t)v * 4 + h];

    float acc0 = 0.f, acc1 = 0.f, ssum = 0.f;
    const float2* feat2 = (const float2*)feat;

    for (int i = start; i < end; i += 4) {
        int last = end - 1;
        int i1 = (i + 1 < end) ? i + 1 : last;
        int i2 = (i + 2 < end) ? i + 2 : last;
        int i3 = (i + 3 < end) ? i + 3 : last;
        float m1 = (i + 1 < end) ? 1.f : 0.f;
        float m2 = (i + 2 < end) ? 1.f : 0.f;
        float m3 = (i + 3 < end) ? 1.f : 0.f;
        int2 c0 = csr[i];
        int2 c1 = csr[i1];
        int2 c2 = csr[i2];
        int2 c3 = csr[i3];
        int s0 = c0.x, s1 = c1.x, s2 = c2.x, s3 = c3.x;
        // all independent loads first (4-deep MLP)
        float el0 = el[(size_t)s0 * 4 + h];
        float el1 = el[(size_t)s1 * 4 + h];
        float el2 = el[(size_t)s2 * 4 + h];
        float el3 = el[(size_t)s3 * 4 + h];
        float2 f0 = feat2[(size_t)s0 * 64 + lane];
        float2 f1 = feat2[(size_t)s1 * 64 + lane];
        float2 f2 = feat2[(size_t)s2 * 64 + lane];
        float2 f3 = feat2[(size_t)s3 * 64 + lane];
        float p0 = __expf(leaky(el0 + er_h));
        float p1 = m1 * __expf(leaky(el1 + er_h));
        float p2 = m2 * __expf(leaky(el2 + er_h));
        float p3 = m3 * __expf(leaky(el3 + er_h));
        ssum += (p0 + p1) + (p2 + p3);
        float w0 = p0 * __int_as_float(c0.y);
        float w1 = p1 * __int_as_float(c1.y);
        float w2 = p2 * __int_as_float(c2.y);
        float w3 = p3 * __int_as_float(c3.y);
        acc0 = fmaf(w0, f0.x, acc0); acc1 = fmaf(w0, f0.y, acc1);
        acc0 = fmaf(w1, f1.x, acc0); acc1 = fmaf(w1, f1.y, acc1);
        acc0 = fmaf(w2, f2.x, acc0); acc1 = fmaf(w2, f2.y, acc1);
        acc0 = fmaf(w3, f3.x, acc0); acc1 = fmaf(w3, f3.y, acc1);
    }

    float inv = 1.f / fmaxf(ssum, 1e-20f);
    int f0i = lane * 2;
    float2 bv = *(const float2*)(bias + f0i);
    float o0 = fmaf(acc0, inv, bv.x);
    float o1 = fmaf(acc1, inv, bv.y);
    o0 = o0 > 0.f ? o0 : __expf(o0) - 1.f;
    o1 = o1 > 0.f ? o1 : __expf(o1) - 1.f;
    *(float2*)(out + (size_t)v * 128 + f0i) = make_float2(o0, o1);
}

// ---------------- launch ----------------
extern "C" void kernel_launch(void* const* d_in, const int* in_sizes, int n_in,
                              void* d_out, int out_size, void* d_ws, size_t ws_size,
                              hipStream_t stream) {
    int n_nodes = in_sizes[0] / 128;
    int n_edges = in_sizes[1];

    const float* in_feat = (const float*)d_in[0];
    const float* ew = (const float*)d_in[1];
    const int* src = (const int*)d_in[2];
    const int* dst = (const int*)d_in[3];
    const float* W0 = (const float*)d_in[4];
    const float* al0 = (const float*)d_in[5];
    const float* ar0 = (const float*)d_in[6];
    const float* b0 = (const float*)d_in[7];
    const float* W1 = (const float*)d_in[8];
    const float* al1 = (const float*)d_in[9];
    const float* ar1 = (const float*)d_in[10];
    const float* b1 = (const float*)d_in[11];
    float* out = (float*)d_out;

    char* w = (char*)d_ws;
    auto alloc = [&](size_t bytes) {
        char* p = w;
        w += (bytes + 255) & ~(size_t)255;
        return p;
    };
    float* feat = (float*)alloc((size_t)n_nodes * 128 * 4);
    float* h1 = (float*)alloc((size_t)n_nodes * 128 * 4);
    float* el = (float*)alloc((size_t)n_nodes * 4 * 4);
    float* er = (float*)alloc((size_t)n_nodes * 4 * 4);
    int* deg = (int*)alloc((size_t)n_nodes * 4);
    int* row_ptr = (int*)alloc(((size_t)n_nodes + 1) * 4);
    int* cursor = (int*)alloc((size_t)n_nodes * 4);
    int* bsum = (int*)alloc(SCAN_BS * 4);
    int* boff = (int*)alloc(SCAN_BS * 4);
    int2* csr = (int2*)alloc((size_t)n_edges * 8);

    int tb = 256;
    int gb_n = (n_nodes + tb - 1) / tb;
    int gb_e = (n_edges + tb - 1) / tb;
    int nb = (n_nodes + SCAN_BS - 1) / SCAN_BS;

    // CSR build (dst-sorted adjacency), rebuilt every call
    k_zero<<<gb_n, tb, 0, stream>>>(deg, n_nodes);
    k_hist<<<gb_e, tb, 0, stream>>>(dst, deg, n_edges);
    k_scan1<<<nb, SCAN_BS, 0, stream>>>(deg, row_ptr, bsum, n_nodes);
    k_scan2<<<1, SCAN_BS, 0, stream>>>(bsum, boff, nb);
    k_scan3<<<gb_n, tb, 0, stream>>>(row_ptr, boff, cursor, n_nodes);
    k_scatter<<<gb_e, tb, 0, stream>>>(src, dst, ew, cursor, csr, n_edges);

    dim3 gg((n_nodes + 63) / 64, 2);
    int ge = (n_nodes + 3) / 4;

    // layer 1
    k_gemm<<<gg, 256, 0, stream>>>(in_feat, W0, feat, al0, ar0, el, er, n_nodes);
    k_edge<<<ge, 256, 0, stream>>>(row_ptr, csr, feat, el, er, b0, h1, n_nodes);

    // layer 2
    k_gemm<<<gg, 256, 0, stream>>>(h1, W1, feat, al1, ar1, el, er, n_nodes);
    k_edge<<<ge, 256, 0, stream>>>(row_ptr, csr, feat, el, er, b1, out, n_nodes);
}

// Round 8
// 1066.963 us; speedup vs baseline: 1.2141x; 1.0111x over previous
//
#include <hip/hip_runtime.h>
#include <math.h>

#define NEG_SLOPE 0.2f
#define SCAN_BS 1024

static __device__ __forceinline__ float leaky(float x) { return fmaxf(x, NEG_SLOPE * x); }

// ---------------- CSR build ----------------
__global__ void k_zero(int* p, int n) {
    int i = blockIdx.x * blockDim.x + threadIdx.x;
    if (i < n) p[i] = 0;
}

__global__ void k_hist(const int* __restrict__ dst, int* __restrict__ deg, int n_edges) {
    int e = blockIdx.x * blockDim.x + threadIdx.x;
    if (e < n_edges) atomicAdd(&deg[dst[e]], 1);
}

__global__ void k_scan1(const int* __restrict__ deg, int* __restrict__ row_ptr,
                        int* __restrict__ bsum, int n) {
    __shared__ int s[SCAN_BS];
    int t = threadIdx.x;
    int idx = blockIdx.x * SCAN_BS + t;
    int v = (idx < n) ? deg[idx] : 0;
    s[t] = v;
    __syncthreads();
    for (int off = 1; off < SCAN_BS; off <<= 1) {
        int x = (t >= off) ? s[t - off] : 0;
        __syncthreads();
        s[t] += x;
        __syncthreads();
    }
    if (idx < n) row_ptr[idx + 1] = s[t];
    if (t == SCAN_BS - 1) bsum[blockIdx.x] = s[t];
    if (idx == 0) row_ptr[0] = 0;
}

__global__ void k_scan2(const int* __restrict__ bsum, int* __restrict__ boff, int nb) {
    __shared__ int s[SCAN_BS];
    int t = threadIdx.x;
    int v = (t < nb) ? bsum[t] : 0;
    s[t] = v;
    __syncthreads();
    for (int off = 1; off < SCAN_BS; off <<= 1) {
        int x = (t >= off) ? s[t - off] : 0;
        __syncthreads();
        s[t] += x;
        __syncthreads();
    }
    if (t < nb) boff[t] = s[t] - v;  // exclusive
}

__global__ void k_scan3(int* __restrict__ row_ptr, const int* __restrict__ boff,
                        int* __restrict__ cursor, int n) {
    int idx = blockIdx.x * blockDim.x + threadIdx.x;
    if (idx < n) {
        int fin = row_ptr[idx + 1] + boff[idx >> 10];
        row_ptr[idx + 1] = fin;
        if (idx + 1 < n) cursor[idx + 1] = fin;
        if (idx == 0) cursor[0] = 0;
    }
}

__global__ void k_scatter(const int* __restrict__ src, const int* __restrict__ dst,
                          const float* __restrict__ ew, int* __restrict__ cursor,
                          int2* __restrict__ csr, int n_edges) {
    int e = blockIdx.x * blockDim.x + threadIdx.x;
    if (e < n_edges) {
        int d = dst[e];
        int p = atomicAdd(&cursor[d], 1);
        csr[p] = make_int2(src[e], __float_as_int(ew[e]));
    }
}

// ---------------- GEMM + fused attention scores (streamed A) ----------------
// C[n][128] = A[n][128] * B[128][128]. Only Bs in LDS (the round-2 As tile had
// a structural 4-way bank conflict: row stride 128 ≡ 0 mod 32 banks).
// A-fragments broadcast-load from global (16-lane broadcast, L1-resident).
// 64x64 tile, block 256, 4x4 per thread; inner loop is pure-fma bound.
__global__ __launch_bounds__(256) void k_gemm(const float* __restrict__ A,
                                              const float* __restrict__ B,
                                              float* __restrict__ C,
                                              const float* __restrict__ al,
                                              const float* __restrict__ ar,
                                              float* __restrict__ el,
                                              float* __restrict__ er, int n) {
    __shared__ float Bs[128 * 64];  // Bs[k][c]
    int t = threadIdx.x;
    int row0 = blockIdx.x * 64;
    int colbase = blockIdx.y * 64;

    // stage B strip
    {
        int c0 = (t & 15) * 4;
        int kr = t >> 4;  // 0..15
        for (int it = 0; it < 8; ++it) {
            int k = kr + it * 16;
            float4 v = *(const float4*)(B + (size_t)k * 128 + colbase + c0);
            *(float4*)(Bs + k * 64 + c0) = v;
        }
    }
    __syncthreads();

    int r0 = row0 + (t >> 4) * 4;
    int c0 = (t & 15) * 4;
    const float* Ar0 = A + (size_t)((r0 + 0) < n ? (r0 + 0) : 0) * 128;
    const float* Ar1 = A + (size_t)((r0 + 1) < n ? (r0 + 1) : 0) * 128;
    const float* Ar2 = A + (size_t)((r0 + 2) < n ? (r0 + 2) : 0) * 128;
    const float* Ar3 = A + (size_t)((r0 + 3) < n ? (r0 + 3) : 0) * 128;

    float acc[4][4];
#pragma unroll
    for (int i = 0; i < 4; i++)
#pragma unroll
        for (int j = 0; j < 4; j++) acc[i][j] = 0.f;

#pragma unroll 2
    for (int k = 0; k < 128; k += 4) {
        float4 a0 = *(const float4*)(Ar0 + k);
        float4 a1 = *(const float4*)(Ar1 + k);
        float4 a2 = *(const float4*)(Ar2 + k);
        float4 a3 = *(const float4*)(Ar3 + k);
#pragma unroll
        for (int kk = 0; kk < 4; kk++) {
            float4 b = *(const float4*)(Bs + (k + kk) * 64 + c0);
            float e0 = kk == 0 ? a0.x : kk == 1 ? a0.y : kk == 2 ? a0.z : a0.w;
            float e1 = kk == 0 ? a1.x : kk == 1 ? a1.y : kk == 2 ? a1.z : a1.w;
            float e2 = kk == 0 ? a2.x : kk == 1 ? a2.y : kk == 2 ? a2.z : a2.w;
            float e3 = kk == 0 ? a3.x : kk == 1 ? a3.y : kk == 2 ? a3.z : a3.w;
            acc[0][0] = fmaf(e0, b.x, acc[0][0]); acc[0][1] = fmaf(e0, b.y, acc[0][1]);
            acc[0][2] = fmaf(e0, b.z, acc[0][2]); acc[0][3] = fmaf(e0, b.w, acc[0][3]);
            acc[1][0] = fmaf(e1, b.x, acc[1][0]); acc[1][1] = fmaf(e1, b.y, acc[1][1]);
            acc[1][2] = fmaf(e1, b.z, acc[1][2]); acc[1][3] = fmaf(e1, b.w, acc[1][3]);
            acc[2][0] = fmaf(e2, b.x, acc[2][0]); acc[2][1] = fmaf(e2, b.y, acc[2][1]);
            acc[2][2] = fmaf(e2, b.z, acc[2][2]); acc[2][3] = fmaf(e2, b.w, acc[2][3]);
            acc[3][0] = fmaf(e3, b.x, acc[3][0]); acc[3][1] = fmaf(e3, b.y, acc[3][1]);
            acc[3][2] = fmaf(e3, b.z, acc[3][2]); acc[3][3] = fmaf(e3, b.w, acc[3][3]);
        }
    }

#pragma unroll
    for (int i = 0; i < 4; i++) {
        int r = r0 + i;
        if (r < n) {
            float4 v = make_float4(acc[i][0], acc[i][1], acc[i][2], acc[i][3]);
            *(float4*)(C + (size_t)r * 128 + colbase + c0) = v;
        }
    }

    // fused el/er: strip covers heads 2*by, 2*by+1; 8 consecutive lanes share
    // (row group, head) -> shfl reduce.
    {
        int hg = blockIdx.y * 2 + ((t >> 3) & 1);
        float4 a4 = *(const float4*)(al + hg * 32 + (t & 7) * 4);
        float4 b4 = *(const float4*)(ar + hg * 32 + (t & 7) * 4);
        float pel[4], per[4];
#pragma unroll
        for (int i = 0; i < 4; i++) {
            pel[i] = acc[i][0] * a4.x + acc[i][1] * a4.y + acc[i][2] * a4.z + acc[i][3] * a4.w;
            per[i] = acc[i][0] * b4.x + acc[i][1] * b4.y + acc[i][2] * b4.z + acc[i][3] * b4.w;
        }
#pragma unroll
        for (int m = 1; m < 8; m <<= 1) {
#pragma unroll
            for (int i = 0; i < 4; i++) {
                pel[i] += __shfl_xor(pel[i], m);
                per[i] += __shfl_xor(per[i], m);
            }
        }
        if ((t & 7) == 0) {
#pragma unroll
            for (int i = 0; i < 4; i++) {
                int r = r0 + i;
                if (r < n) {
                    el[(size_t)r * 4 + hg] = pel[i];
                    er[(size_t)r * 4 + hg] = per[i];
                }
            }
        }
    }
}

// ---------------- per-dst-node softmax + aggregate ----------------
// TWO nodes per wave: each 32-lane half owns one node; lane li owns floats
// 4*li..4*li+3 (float4), head h = li>>3. Every overhead instruction (csr,
// el, exp) now serves 2 edges per wave. ssum per lane covers all of its
// node's edges (masked full-trip loop) — no reduction, no LDS, no barriers.
// Unpadded CSR: clamped indices + zero masks for the tail.
__global__ __launch_bounds__(256) void k_edge(const int* __restrict__ row_ptr,
                                              const int2* __restrict__ csr,
                                              const float* __restrict__ feat,
                                              const float* __restrict__ el,
                                              const float* __restrict__ er,
                                              const float* __restrict__ bias,
                                              float* __restrict__ out, int n) {
    int wv = threadIdx.x >> 6;
    int lane = threadIdx.x & 63;
    int sub = lane >> 5;   // which node of this wave's pair
    int li = lane & 31;    // feature lane
    int h = li >> 3;       // head
    int v = blockIdx.x * 8 + wv * 2 + sub;
    bool active = v < n;
    int vc = active ? v : n - 1;

    int start = row_ptr[vc];
    int end = active ? row_ptr[vc + 1] : start;
    float er_h = er[(size_t)vc * 4 + h];

    int myT = (end - start + 3) >> 2;
    int otherT = __shfl(myT, lane ^ 32);
    int maxT = myT > otherT ? myT : otherT;

    int last = end - 1;
    if (last < start) last = start;  // deg-0 half: reads csr[start] (masked); start<n_edges or within pad

    float4 acc = make_float4(0.f, 0.f, 0.f, 0.f);
    float ssum = 0.f;
    const float4* feat4 = (const float4*)feat;

    for (int j = 0; j < maxT; ++j) {
        int i = start + j * 4;
        int i0 = i < last ? i : last;
        int i1 = i + 1 < last ? i + 1 : last;
        int i2 = i + 2 < last ? i + 2 : last;
        int i3 = i + 3 < last ? i + 3 : last;
        float m0 = (i < end) ? 1.f : 0.f;
        float m1 = (i + 1 < end) ? 1.f : 0.f;
        float m2 = (i + 2 < end) ? 1.f : 0.f;
        float m3 = (i + 3 < end) ? 1.f : 0.f;
        int2 c0 = csr[i0];
        int2 c1 = csr[i1];
        int2 c2 = csr[i2];
        int2 c3 = csr[i3];
        // all independent loads first (4-deep MLP)
        float el0 = el[(size_t)c0.x * 4 + h];
        float el1 = el[(size_t)c1.x * 4 + h];
        float el2 = el[(size_t)c2.x * 4 + h];
        float el3 = el[(size_t)c3.x * 4 + h];
        float4 f0 = feat4[(size_t)c0.x * 32 + li];
        float4 f1 = feat4[(size_t)c1.x * 32 + li];
        float4 f2 = feat4[(size_t)c2.x * 32 + li];
        float4 f3 = feat4[(size_t)c3.x * 32 + li];
        float p0 = m0 * __expf(leaky(el0 + er_h));
        float p1 = m1 * __expf(leaky(el1 + er_h));
        float p2 = m2 * __expf(leaky(el2 + er_h));
        float p3 = m3 * __expf(leaky(el3 + er_h));
        ssum += (p0 + p1) + (p2 + p3);
        float w0 = p0 * __int_as_float(c0.y);
        float w1 = p1 * __int_as_float(c1.y);
        float w2 = p2 * __int_as_float(c2.y);
        float w3 = p3 * __int_as_float(c3.y);
        acc.x = fmaf(w0, f0.x, acc.x); acc.y = fmaf(w0, f0.y, acc.y);
        acc.z = fmaf(w0, f0.z, acc.z); acc.w = fmaf(w0, f0.w, acc.w);
        acc.x = fmaf(w1, f1.x, acc.x); acc.y = fmaf(w1, f1.y, acc.y);
        acc.z = fmaf(w1, f1.z, acc.z); acc.w = fmaf(w1, f1.w, acc.w);
        acc.x = fmaf(w2, f2.x, acc.x); acc.y = fmaf(w2, f2.y, acc.y);
        acc.z = fmaf(w2, f2.z, acc.z); acc.w = fmaf(w2, f2.w, acc.w);
        acc.x = fmaf(w3, f3.x, acc.x); acc.y = fmaf(w3, f3.y, acc.y);
        acc.z = fmaf(w3, f3.z, acc.z); acc.w = fmaf(w3, f3.w, acc.w);
    }

    if (active) {
        float inv = 1.f / fmaxf(ssum, 1e-20f);
        float4 bv = *(const float4*)(bias + li * 4);
        float o0 = fmaf(acc.x, inv, bv.x);
        float o1 = fmaf(acc.y, inv, bv.y);
        float o2 = fmaf(acc.z, inv, bv.z);
        float o3 = fmaf(acc.w, inv, bv.w);
        o0 = o0 > 0.f ? o0 : __expf(o0) - 1.f;
        o1 = o1 > 0.f ? o1 : __expf(o1) - 1.f;
        o2 = o2 > 0.f ? o2 : __expf(o2) - 1.f;
        o3 = o3 > 0.f ? o3 : __expf(o3) - 1.f;
        *(float4*)(out + (size_t)v * 128 + li * 4) = make_float4(o0, o1, o2, o3);
    }
}

// ---------------- launch ----------------
extern "C" void kernel_launch(void* const* d_in, const int* in_sizes, int n_in,
                              void* d_out, int out_size, void* d_ws, size_t ws_size,
                              hipStream_t stream) {
    int n_nodes = in_sizes[0] / 128;
    int n_edges = in_sizes[1];

    const float* in_feat = (const float*)d_in[0];
    const float* ew = (const float*)d_in[1];
    const int* src = (const int*)d_in[2];
    const int* dst = (const int*)d_in[3];
    const float* W0 = (const float*)d_in[4];
    const float* al0 = (const float*)d_in[5];
    const float* ar0 = (const float*)d_in[6];
    const float* b0 = (const float*)d_in[7];
    const float* W1 = (const float*)d_in[8];
    const float* al1 = (const float*)d_in[9];
    const float* ar1 = (const float*)d_in[10];
    const float* b1 = (const float*)d_in[11];
    float* out = (float*)d_out;

    char* w = (char*)d_ws;
    auto alloc = [&](size_t bytes) {
        char* p = w;
        w += (bytes + 255) & ~(size_t)255;
        return p;
    };
    float* feat = (float*)alloc((size_t)n_nodes * 128 * 4);
    float* h1 = (float*)alloc((size_t)n_nodes * 128 * 4);
    float* el = (float*)alloc((size_t)n_nodes * 4 * 4);
    float* er = (float*)alloc((size_t)n_nodes * 4 * 4);
    int* deg = (int*)alloc((size_t)n_nodes * 4);
    int* row_ptr = (int*)alloc(((size_t)n_nodes + 1) * 4);
    int* cursor = (int*)alloc((size_t)n_nodes * 4);
    int* bsum = (int*)alloc(SCAN_BS * 4);
    int* boff = (int*)alloc(SCAN_BS * 4);
    int2* csr = (int2*)alloc((size_t)n_edges * 8);

    int tb = 256;
    int gb_n = (n_nodes + tb - 1) / tb;
    int gb_e = (n_edges + tb - 1) / tb;
    int nb = (n_nodes + SCAN_BS - 1) / SCAN_BS;

    // CSR build (dst-sorted adjacency), rebuilt every call
    k_zero<<<gb_n, tb, 0, stream>>>(deg, n_nodes);
    k_hist<<<gb_e, tb, 0, stream>>>(dst, deg, n_edges);
    k_scan1<<<nb, SCAN_BS, 0, stream>>>(deg, row_ptr, bsum, n_nodes);
    k_scan2<<<1, SCAN_BS, 0, stream>>>(bsum, boff, nb);
    k_scan3<<<gb_n, tb, 0, stream>>>(row_ptr, boff, cursor, n_nodes);
    k_scatter<<<gb_e, tb, 0, stream>>>(src, dst, ew, cursor, csr, n_edges);

    dim3 gg((n_nodes + 63) / 64, 2);
    int ge = (n_nodes + 7) / 8;

    // layer 1
    k_gemm<<<gg, 256, 0, stream>>>(in_feat, W0, feat, al0, ar0, el, er, n_nodes);
    k_edge<<<ge, 256, 0, stream>>>(row_ptr, csr, feat, el, er, b0, h1, n_nodes);

    // layer 2
    k_gemm<<<gg, 256, 0, stream>>>(h1, W1, feat, al1, ar1, el, er, n_nodes);
    k_edge<<<ge, 256, 0, stream>>>(row_ptr, csr, feat, el, er, b1, out, n_nodes);
}